// Round 1
// baseline (1111.614 us; speedup 1.0000x reference)
//
#include <hip/hip_runtime.h>
#include <math.h>

#define E_DIM 1024
#define NH 16
#define DH 64
#define BSEG 8
#define LQ 512
#define LKV 1024

// ---------------------------------------------------------------------------
// GEMM: C[M,N] = A[M,K] @ W[N,K]^T + bias[N]   (all row-major, fp32)
// 64x64 block tile, BK=16, 256 threads, 4x4 micro-tile per thread.
// ---------------------------------------------------------------------------
__global__ __launch_bounds__(256) void gemm_bias_kernel(
    const float* __restrict__ A, const float* __restrict__ W,
    const float* __restrict__ bias, float* __restrict__ C,
    int M, int N, int K)
{
    const int BM = 64, BN = 64, BK = 16;
    __shared__ float As[16][64 + 4];   // transposed: As[k][m], pad keeps 16B align
    __shared__ float Ws[16][64 + 4];   // transposed: Ws[k][n]

    const int bx = blockIdx.x;          // N tile
    const int by = blockIdx.y;          // M tile
    const int tid = threadIdx.x;
    const int tx = tid & 15;            // 0..15 -> n
    const int ty = tid >> 4;            // 0..15 -> m

    const float* Ab = A + (size_t)(by * BM) * K;
    const float* Wb = W + (size_t)(bx * BN) * K;

    float acc[4][4] = {};

    const int lr = tid >> 2;            // 0..63 (row within tile)
    const int lc = (tid & 3) * 4;       // 0,4,8,12 (k within BK)

    for (int k0 = 0; k0 < K; k0 += BK) {
        float4 va = *(const float4*)(Ab + (size_t)lr * K + k0 + lc);
        float4 vw = *(const float4*)(Wb + (size_t)lr * K + k0 + lc);
        As[lc + 0][lr] = va.x; As[lc + 1][lr] = va.y;
        As[lc + 2][lr] = va.z; As[lc + 3][lr] = va.w;
        Ws[lc + 0][lr] = vw.x; Ws[lc + 1][lr] = vw.y;
        Ws[lc + 2][lr] = vw.z; Ws[lc + 3][lr] = vw.w;
        __syncthreads();

        #pragma unroll
        for (int kk = 0; kk < BK; ++kk) {
            float4 a4 = *(const float4*)&As[kk][ty * 4];
            float4 b4 = *(const float4*)&Ws[kk][tx * 4];
            float a[4] = {a4.x, a4.y, a4.z, a4.w};
            float b[4] = {b4.x, b4.y, b4.z, b4.w};
            #pragma unroll
            for (int i = 0; i < 4; ++i)
                #pragma unroll
                for (int j = 0; j < 4; ++j)
                    acc[i][j] = fmaf(a[i], b[j], acc[i][j]);
        }
        __syncthreads();
    }

    const int n0 = bx * BN + tx * 4;
    float4 bb = *(const float4*)(bias + n0);
    #pragma unroll
    for (int i = 0; i < 4; ++i) {
        int m = by * BM + ty * 4 + i;
        float4 v;
        v.x = acc[i][0] + bb.x;
        v.y = acc[i][1] + bb.y;
        v.z = acc[i][2] + bb.z;
        v.w = acc[i][3] + bb.w;
        *(float4*)(C + (size_t)m * N + n0) = v;
    }
}

// ---------------------------------------------------------------------------
// Flash-style attention over packed uniform segments.
// grid: (LQ/64, NH, BSEG); block 256. Q,K,V,O are [tokens, E] fp32, head h at
// column h*DH. Each block: 64 q-rows x full DH for one (b,h); loops kv in 64s.
// ---------------------------------------------------------------------------
__global__ __launch_bounds__(256) void attn_kernel(
    const float* __restrict__ Q, const float* __restrict__ K,
    const float* __restrict__ V, float* __restrict__ O)
{
    const int qt = blockIdx.x;
    const int h  = blockIdx.y;
    const int b  = blockIdx.z;

    const int tid = threadIdx.x;
    const int tx = tid & 15;
    const int ty = tid >> 4;

    __shared__ float Qst[DH][64 + 4];   // transposed: [d][qrow]
    __shared__ float Kst[DH][64 + 4];   // transposed: [d][kvrow]
    __shared__ float Vs[64][DH + 4];    // row-major:  [kvrow][d]
    __shared__ float Ps[64][64 + 4];    // [qrow][kvrow]

    const int qrow0 = b * LQ + qt * 64;
    const int col0  = h * DH;

    // load Q tile (transposed into LDS)
    {
        const int c = (tid & 15) * 4;
        #pragma unroll
        for (int it = 0; it < 4; ++it) {
            int r = (tid >> 4) + it * 16;
            float4 v = *(const float4*)(Q + (size_t)(qrow0 + r) * E_DIM + col0 + c);
            Qst[c + 0][r] = v.x; Qst[c + 1][r] = v.y;
            Qst[c + 2][r] = v.z; Qst[c + 3][r] = v.w;
        }
    }

    float m_i[4], l_i[4], o[4][4];
    #pragma unroll
    for (int i = 0; i < 4; ++i) {
        m_i[i] = -1e30f; l_i[i] = 0.f;
        #pragma unroll
        for (int j = 0; j < 4; ++j) o[i][j] = 0.f;
    }

    const float scale = 0.125f;   // 1/sqrt(64)

    for (int kv0 = 0; kv0 < LKV; kv0 += 64) {
        __syncthreads();   // protect Kst/Vs from previous iteration readers
        {
            const int c = (tid & 15) * 4;
            const int krow0 = b * LKV + kv0;
            #pragma unroll
            for (int it = 0; it < 4; ++it) {
                int r = (tid >> 4) + it * 16;
                float4 vk = *(const float4*)(K + (size_t)(krow0 + r) * E_DIM + col0 + c);
                Kst[c + 0][r] = vk.x; Kst[c + 1][r] = vk.y;
                Kst[c + 2][r] = vk.z; Kst[c + 3][r] = vk.w;
                float4 vv = *(const float4*)(V + (size_t)(krow0 + r) * E_DIM + col0 + c);
                *(float4*)&Vs[r][c] = vv;
            }
        }
        __syncthreads();

        // S = Q K^T (64x64 distributed 4x4 per thread)
        float s[4][4] = {};
        #pragma unroll 4
        for (int d = 0; d < DH; ++d) {
            float4 a4 = *(const float4*)&Qst[d][ty * 4];
            float4 b4 = *(const float4*)&Kst[d][tx * 4];
            float a[4] = {a4.x, a4.y, a4.z, a4.w};
            float bb[4] = {b4.x, b4.y, b4.z, b4.w};
            #pragma unroll
            for (int i = 0; i < 4; ++i)
                #pragma unroll
                for (int j = 0; j < 4; ++j)
                    s[i][j] = fmaf(a[i], bb[j], s[i][j]);
        }

        // online softmax (row = q index; reduce across the 16 tx lanes)
        #pragma unroll
        for (int i = 0; i < 4; ++i) {
            float rm = s[i][0];
            rm = fmaxf(rm, s[i][1]); rm = fmaxf(rm, s[i][2]); rm = fmaxf(rm, s[i][3]);
            rm *= scale;
            #pragma unroll
            for (int off = 8; off; off >>= 1)
                rm = fmaxf(rm, __shfl_xor(rm, off, 16));
            float mnew = fmaxf(m_i[i], rm);
            float alpha = __expf(m_i[i] - mnew);
            float p[4], rs = 0.f;
            #pragma unroll
            for (int j = 0; j < 4; ++j) {
                p[j] = __expf(fmaf(s[i][j], scale, -mnew));
                rs += p[j];
            }
            #pragma unroll
            for (int off = 8; off; off >>= 1)
                rs += __shfl_xor(rs, off, 16);
            l_i[i] = l_i[i] * alpha + rs;
            m_i[i] = mnew;
            #pragma unroll
            for (int j = 0; j < 4; ++j) o[i][j] *= alpha;
            float4 pv = {p[0], p[1], p[2], p[3]};
            *(float4*)&Ps[ty * 4 + i][tx * 4] = pv;
        }
        __syncthreads();

        // O += P @ V
        #pragma unroll 2
        for (int k0 = 0; k0 < 64; k0 += 4) {
            float a[4][4];
            #pragma unroll
            for (int i = 0; i < 4; ++i) {
                float4 t = *(const float4*)&Ps[ty * 4 + i][k0];
                a[i][0] = t.x; a[i][1] = t.y; a[i][2] = t.z; a[i][3] = t.w;
            }
            #pragma unroll
            for (int kk = 0; kk < 4; ++kk) {
                float4 b4 = *(const float4*)&Vs[k0 + kk][tx * 4];
                #pragma unroll
                for (int i = 0; i < 4; ++i) {
                    o[i][0] = fmaf(a[i][kk], b4.x, o[i][0]);
                    o[i][1] = fmaf(a[i][kk], b4.y, o[i][1]);
                    o[i][2] = fmaf(a[i][kk], b4.z, o[i][2]);
                    o[i][3] = fmaf(a[i][kk], b4.w, o[i][3]);
                }
            }
        }
    }

    // epilogue: divide by l, store
    #pragma unroll
    for (int i = 0; i < 4; ++i) {
        float inv = 1.0f / l_i[i];
        float4 v = {o[i][0] * inv, o[i][1] * inv, o[i][2] * inv, o[i][3] * inv};
        *(float4*)(O + (size_t)(qrow0 + ty * 4 + i) * E_DIM + col0 + tx * 4) = v;
    }
}

// ---------------------------------------------------------------------------
extern "C" void kernel_launch(void* const* d_in, const int* in_sizes, int n_in,
                              void* d_out, int out_size, void* d_ws, size_t ws_size,
                              hipStream_t stream) {
    const float* inputs  = (const float*)d_in[0];   // [8192,1024]
    const float* queries = (const float*)d_in[1];   // [4096,1024]
    const float* w_in    = (const float*)d_in[2];   // [3072,1024]
    const float* b_in    = (const float*)d_in[3];   // [3072]
    const float* w_out   = (const float*)d_in[4];   // [1024,1024]
    const float* b_out   = (const float*)d_in[5];   // [1024]
    float* out = (float*)d_out;                     // [4096,1024]

    const int NQ = BSEG * LQ;    // 4096
    const int NKV = BSEG * LKV;  // 8192

    // workspace layout (fp32): Q | K | V | O  = 16+32+32+16 = 96 MB
    float* Qp = (float*)d_ws;
    float* Kp = Qp + (size_t)NQ * E_DIM;
    float* Vp = Kp + (size_t)NKV * E_DIM;
    float* Op = Vp + (size_t)NKV * E_DIM;

    dim3 blk(256);

    // projections
    gemm_bias_kernel<<<dim3(E_DIM / 64, NQ / 64), blk, 0, stream>>>(
        queries, w_in, b_in, Qp, NQ, E_DIM, E_DIM);
    gemm_bias_kernel<<<dim3(E_DIM / 64, NKV / 64), blk, 0, stream>>>(
        inputs, w_in + (size_t)E_DIM * E_DIM, b_in + E_DIM, Kp, NKV, E_DIM, E_DIM);
    gemm_bias_kernel<<<dim3(E_DIM / 64, NKV / 64), blk, 0, stream>>>(
        inputs, w_in + (size_t)2 * E_DIM * E_DIM, b_in + 2 * E_DIM, Vp, NKV, E_DIM, E_DIM);

    // attention
    attn_kernel<<<dim3(LQ / 64, NH, BSEG), blk, 0, stream>>>(Qp, Kp, Vp, Op);

    // output projection
    gemm_bias_kernel<<<dim3(E_DIM / 64, NQ / 64), blk, 0, stream>>>(
        Op, w_out, b_out, out, NQ, E_DIM, E_DIM);
}

// Round 2
// 300.760 us; speedup vs baseline: 3.6960x; 3.6960x over previous
//
#include <hip/hip_runtime.h>

#define E_DIM 1024
#define NH 16
#define DH 64
#define BSEG 8
#define LQ 512
#define LKV 1024

typedef short bf16x8 __attribute__((ext_vector_type(8)));
typedef float f32x4 __attribute__((ext_vector_type(4)));
typedef unsigned short u16;

// round-to-nearest-even fp32 -> bf16 bits
__device__ __forceinline__ u16 f2bf(float x) {
    unsigned u = __float_as_uint(x);
    u += 0x7FFF + ((u >> 16) & 1);
    return (u16)(u >> 16);
}

// async global->LDS, 16B per lane; lds dest must be wave-uniform base
__device__ __forceinline__ void async16(const void* g, const void* l) {
    __builtin_amdgcn_global_load_lds(
        (const __attribute__((address_space(1))) unsigned int*)g,
        (__attribute__((address_space(3))) unsigned int*)l, 16, 0, 0);
}

// ---------------------------------------------------------------------------
// fp32 -> bf16 elementwise convert (n must be multiple of 1024)
// ---------------------------------------------------------------------------
__global__ __launch_bounds__(256) void cvt_bf16_kernel(
    const float* __restrict__ s, u16* __restrict__ d)
{
    int i = blockIdx.x * 256 + threadIdx.x;
    float4 v = ((const float4*)s)[i];
    ushort4 o;
    o.x = f2bf(v.x); o.y = f2bf(v.y); o.z = f2bf(v.z); o.w = f2bf(v.w);
    ((ushort4*)d)[i] = o;
}

// ---------------------------------------------------------------------------
// bf16 MFMA GEMM: C[M,N] = A[M,K] @ W[N,K]^T + bias
// 128x128 tile, BK=32, 256 threads (4 waves, each 64x64).
// MODE 0: bf16 output (Cb). MODE 1: fp32 output (Cf).
// ---------------------------------------------------------------------------
template<int MODE>
__global__ __launch_bounds__(256) void gemm_bf16(
    const u16* __restrict__ A, const u16* __restrict__ W,
    const float* __restrict__ bias, u16* __restrict__ Cb,
    float* __restrict__ Cf, int M, int N, int K)
{
    __shared__ u16 As[128 * 32];
    __shared__ u16 Ws[128 * 32];

    const int tid = threadIdx.x;
    const int l = tid & 63;
    const int w = tid >> 6;
    const int m_blk = blockIdx.y * 128;
    const int n_blk = blockIdx.x * 128;
    const int m0 = (w & 1) * 64;
    const int n0 = (w >> 1) * 64;
    const int quad = l >> 4;
    const int c = l & 15;

    f32x4 acc[4][4];
    #pragma unroll
    for (int i = 0; i < 4; ++i)
        #pragma unroll
        for (int j = 0; j < 4; ++j)
            acc[i][j] = (f32x4){0.f, 0.f, 0.f, 0.f};

    // staging: 8 chunks of 16 rows per tile; wave w does chunks w and w+4
    const int srow = l >> 2;            // 0..15
    const int skoff = (l & 3) * 8;      // 0,8,16,24
    const u16* Ag1 = A + (size_t)(m_blk + w * 16 + srow) * K + skoff;
    const u16* Ag2 = A + (size_t)(m_blk + (w + 4) * 16 + srow) * K + skoff;
    const u16* Wg1 = W + (size_t)(n_blk + w * 16 + srow) * K + skoff;
    const u16* Wg2 = W + (size_t)(n_blk + (w + 4) * 16 + srow) * K + skoff;

    for (int k0 = 0; k0 < K; k0 += 32) {
        __syncthreads();
        async16(Ag1 + k0, As + (size_t)w * 512);
        async16(Ag2 + k0, As + (size_t)(w + 4) * 512);
        async16(Wg1 + k0, Ws + (size_t)w * 512);
        async16(Wg2 + k0, Ws + (size_t)(w + 4) * 512);
        __syncthreads();

        bf16x8 af[4], wf[4];
        #pragma unroll
        for (int t = 0; t < 4; ++t) {
            af[t] = *(const bf16x8*)&As[(m0 + t * 16 + c) * 32 + quad * 8];
            wf[t] = *(const bf16x8*)&Ws[(n0 + t * 16 + c) * 32 + quad * 8];
        }
        #pragma unroll
        for (int i = 0; i < 4; ++i)
            #pragma unroll
            for (int j = 0; j < 4; ++j)
                acc[i][j] = __builtin_amdgcn_mfma_f32_16x16x32_bf16(
                    af[i], wf[j], acc[i][j], 0, 0, 0);
    }

    #pragma unroll
    for (int j = 0; j < 4; ++j) {
        int col = n_blk + n0 + j * 16 + c;
        float bv = bias[col];
        #pragma unroll
        for (int i = 0; i < 4; ++i) {
            int row = m_blk + m0 + i * 16 + quad * 4;
            #pragma unroll
            for (int r = 0; r < 4; ++r) {
                float v = acc[i][j][r] + bv;
                if (MODE == 0) Cb[(size_t)(row + r) * N + col] = f2bf(v);
                else           Cf[(size_t)(row + r) * N + col] = v;
            }
        }
    }
}

// ---------------------------------------------------------------------------
// MFMA flash attention over packed uniform segments (all-bf16 inputs).
// grid (LQ/128, NH, BSEG), 256 threads. Q-tile 128 rows; wave w owns 32 rows.
// Qb: [4096][1024] bf16. KVb: [8192][2048] bf16 (K cols 0..1023, V 1024..2047).
// Ob: [4096][1024] bf16.
// ---------------------------------------------------------------------------
__global__ __launch_bounds__(256) void attn_mfma(
    const u16* __restrict__ Qb, const u16* __restrict__ KVb,
    u16* __restrict__ Ob)
{
    __shared__ u16 Ksh[8 * 512];      // frag-ordered 1KB chunks (t,hk)
    __shared__ u16 Vt[64 * 72];       // transposed V, xor-swizzled 16B granules
    __shared__ u16 Psh[4][32 * 72];   // per-wave P, row-major rowstride 72

    const int tid = threadIdx.x;
    const int l = tid & 63;
    const int w = tid >> 6;
    const int qt = blockIdx.x;
    const int h = blockIdx.y;
    const int b = blockIdx.z;
    const int quad = l >> 4;
    const int c = l & 15;

    const int kcol = h * 64;
    const int vcol = 1024 + h * 64;
    const float C1 = 0.18033688011112042f;  // (1/8) * log2(e)

    // Q A-frags direct from global
    bf16x8 qf[2][2];
    #pragma unroll
    for (int mt = 0; mt < 2; ++mt) {
        int qrow = b * LQ + qt * 128 + w * 32 + mt * 16 + c;
        #pragma unroll
        for (int hk = 0; hk < 2; ++hk)
            qf[mt][hk] = *(const bf16x8*)(Qb + (size_t)qrow * E_DIM + kcol + hk * 32 + quad * 8);
    }

    f32x4 o[2][4];
    float m_i[2][4], l_i[2][4];
    #pragma unroll
    for (int mt = 0; mt < 2; ++mt) {
        #pragma unroll
        for (int t = 0; t < 4; ++t) o[mt][t] = (f32x4){0.f, 0.f, 0.f, 0.f};
        #pragma unroll
        for (int r = 0; r < 4; ++r) { m_i[mt][r] = -1e30f; l_i[mt][r] = 0.f; }
    }

    const int vrow_p = tid >> 3;        // 0..31
    const int vd = (tid & 7) * 8;       // 0..56

    for (int kv0 = 0; kv0 < LKV; kv0 += 64) {
        const int kvg = b * LKV + kv0;
        __syncthreads();
        // K chunks: wave w stages (t=w, hk=0/1); identity read-back = no conflicts
        #pragma unroll
        for (int hk = 0; hk < 2; ++hk)
            async16(KVb + (size_t)(kvg + w * 16 + c) * 2048 + kcol + hk * 32 + quad * 8,
                    Ksh + (w * 2 + hk) * 512);
        // V transpose into swizzled LDS
        #pragma unroll
        for (int p = 0; p < 2; ++p) {
            int row = p * 32 + vrow_p;
            bf16x8 vv = *(const bf16x8*)(KVb + (size_t)(kvg + row) * 2048 + vcol + vd);
            int g = row >> 3;
            #pragma unroll
            for (int e = 0; e < 8; ++e) {
                int d = vd + e;
                Vt[d * 72 + ((g ^ (d >> 3)) & 7) * 8 + (row & 7)] = (u16)vv[e];
            }
        }
        __syncthreads();

        // S = Q K^T
        f32x4 s[2][4];
        #pragma unroll
        for (int mt = 0; mt < 2; ++mt)
            #pragma unroll
            for (int nt = 0; nt < 4; ++nt) s[mt][nt] = (f32x4){0.f, 0.f, 0.f, 0.f};
        #pragma unroll
        for (int hk = 0; hk < 2; ++hk) {
            #pragma unroll
            for (int nt = 0; nt < 4; ++nt) {
                bf16x8 kb = *(const bf16x8*)&Ksh[(nt * 2 + hk) * 512 + l * 8];
                s[0][nt] = __builtin_amdgcn_mfma_f32_16x16x32_bf16(qf[0][hk], kb, s[0][nt], 0, 0, 0);
                s[1][nt] = __builtin_amdgcn_mfma_f32_16x16x32_bf16(qf[1][hk], kb, s[1][nt], 0, 0, 0);
            }
        }

        // online softmax (row reduce across the 16 col-lanes of each quad)
        #pragma unroll
        for (int mt = 0; mt < 2; ++mt) {
            #pragma unroll
            for (int r = 0; r < 4; ++r) {
                float vm = fmaxf(fmaxf(s[mt][0][r], s[mt][1][r]),
                                 fmaxf(s[mt][2][r], s[mt][3][r]));
                vm = fmaxf(vm, __shfl_xor(vm, 1, 16));
                vm = fmaxf(vm, __shfl_xor(vm, 2, 16));
                vm = fmaxf(vm, __shfl_xor(vm, 4, 16));
                vm = fmaxf(vm, __shfl_xor(vm, 8, 16));
                float mnew = fmaxf(m_i[mt][r], vm);
                float alpha = __builtin_amdgcn_exp2f((m_i[mt][r] - mnew) * C1);
                m_i[mt][r] = mnew;
                float pv[4], rs = 0.f;
                #pragma unroll
                for (int nt = 0; nt < 4; ++nt) {
                    pv[nt] = __builtin_amdgcn_exp2f((s[mt][nt][r] - mnew) * C1);
                    rs += pv[nt];
                }
                rs += __shfl_xor(rs, 1, 16);
                rs += __shfl_xor(rs, 2, 16);
                rs += __shfl_xor(rs, 4, 16);
                rs += __shfl_xor(rs, 8, 16);
                l_i[mt][r] = l_i[mt][r] * alpha + rs;
                int q = mt * 16 + quad * 4 + r;
                #pragma unroll
                for (int nt = 0; nt < 4; ++nt) {
                    Psh[w][q * 72 + nt * 16 + c] = f2bf(pv[nt]);
                    o[mt][nt][r] *= alpha;
                }
            }
        }

        // O += P V  (P via per-wave LDS C->A layout transform; V from Vt)
        #pragma unroll
        for (int hk = 0; hk < 2; ++hk) {
            bf16x8 pf0 = *(const bf16x8*)&Psh[w][(c) * 72 + hk * 32 + quad * 8];
            bf16x8 pf1 = *(const bf16x8*)&Psh[w][(16 + c) * 72 + hk * 32 + quad * 8];
            #pragma unroll
            for (int td = 0; td < 4; ++td) {
                int d = td * 16 + c;
                bf16x8 vb = *(const bf16x8*)&Vt[d * 72 + (((hk * 4 + quad) ^ (d >> 3)) & 7) * 8];
                o[0][td] = __builtin_amdgcn_mfma_f32_16x16x32_bf16(pf0, vb, o[0][td], 0, 0, 0);
                o[1][td] = __builtin_amdgcn_mfma_f32_16x16x32_bf16(pf1, vb, o[1][td], 0, 0, 0);
            }
        }
    }

    // epilogue: normalize, store bf16
    #pragma unroll
    for (int mt = 0; mt < 2; ++mt)
        #pragma unroll
        for (int r = 0; r < 4; ++r) {
            float inv = 1.f / l_i[mt][r];
            int row = b * LQ + qt * 128 + w * 32 + mt * 16 + quad * 4 + r;
            #pragma unroll
            for (int nt = 0; nt < 4; ++nt)
                Ob[(size_t)row * E_DIM + h * 64 + nt * 16 + c] = f2bf(o[mt][nt][r] * inv);
        }
}

// ---------------------------------------------------------------------------
extern "C" void kernel_launch(void* const* d_in, const int* in_sizes, int n_in,
                              void* d_out, int out_size, void* d_ws, size_t ws_size,
                              hipStream_t stream) {
    const float* inputs  = (const float*)d_in[0];   // [8192,1024]
    const float* queries = (const float*)d_in[1];   // [4096,1024]
    const float* w_in    = (const float*)d_in[2];   // [3072,1024]
    const float* b_in    = (const float*)d_in[3];   // [3072]
    const float* w_out   = (const float*)d_in[4];   // [1024,1024]
    const float* b_out   = (const float*)d_in[5];   // [1024]
    float* out = (float*)d_out;                     // [4096,1024] fp32

    const int NQ = BSEG * LQ;    // 4096
    const int NKV = BSEG * LKV;  // 8192

    // workspace (all bf16 except none): 80 MB total
    u16* inputs_b  = (u16*)d_ws;                                   // 16 MB
    u16* queries_b = inputs_b  + (size_t)NKV * E_DIM;              //  8 MB
    u16* w_in_b    = queries_b + (size_t)NQ * E_DIM;               //  6 MB
    u16* w_out_b   = w_in_b    + (size_t)3 * E_DIM * E_DIM;        //  2 MB
    u16* Qb        = w_out_b   + (size_t)E_DIM * E_DIM;            //  8 MB
    u16* KVb       = Qb        + (size_t)NQ * E_DIM;               // 32 MB
    u16* Ob        = KVb       + (size_t)NKV * 2 * E_DIM;          //  8 MB

    dim3 blk(256);

    // fp32 -> bf16 conversions
    cvt_bf16_kernel<<<NKV * E_DIM / 1024, blk, 0, stream>>>(inputs, inputs_b);
    cvt_bf16_kernel<<<NQ * E_DIM / 1024, blk, 0, stream>>>(queries, queries_b);
    cvt_bf16_kernel<<<3 * E_DIM * E_DIM / 1024, blk, 0, stream>>>(w_in, w_in_b);
    cvt_bf16_kernel<<<E_DIM * E_DIM / 1024, blk, 0, stream>>>(w_out, w_out_b);

    // Q projection: [4096,1024] = queries @ w_in[0:1024].T
    gemm_bf16<0><<<dim3(E_DIM / 128, NQ / 128), blk, 0, stream>>>(
        queries_b, w_in_b, b_in, Qb, nullptr, NQ, E_DIM, E_DIM);
    // K+V fused projection: [8192,2048] = inputs @ w_in[1024:3072].T
    gemm_bf16<0><<<dim3(2 * E_DIM / 128, NKV / 128), blk, 0, stream>>>(
        inputs_b, w_in_b + (size_t)E_DIM * E_DIM, b_in + E_DIM, KVb, nullptr,
        NKV, 2 * E_DIM, E_DIM);

    // attention
    attn_mfma<<<dim3(LQ / 128, NH, BSEG), blk, 0, stream>>>(Qb, KVb, Ob);

    // output projection (fp32 out)
    gemm_bf16<1><<<dim3(E_DIM / 128, NQ / 128), blk, 0, stream>>>(
        Ob, w_out_b, b_out, nullptr, out, NQ, E_DIM, E_DIM);
}

// Round 4
// 297.089 us; speedup vs baseline: 3.7417x; 1.0124x over previous
//
#include <hip/hip_runtime.h>

#define E_DIM 1024
#define NH 16
#define DH 64
#define BSEG 8
#define LQ 512
#define LKV 1024

typedef short bf16x8 __attribute__((ext_vector_type(8)));
typedef float f32x4 __attribute__((ext_vector_type(4)));
typedef unsigned short u16;

// round-to-nearest-even fp32 -> bf16 bits
__device__ __forceinline__ u16 f2bf(float x) {
    unsigned u = __float_as_uint(x);
    u += 0x7FFF + ((u >> 16) & 1);
    return (u16)(u >> 16);
}

// async global->LDS, 16B per lane; lds dest wave-uniform base + lane*16
__device__ __forceinline__ void async16(const void* g, const void* l) {
    __builtin_amdgcn_global_load_lds(
        (const __attribute__((address_space(1))) unsigned int*)g,
        (__attribute__((address_space(3))) unsigned int*)l, 16, 0, 0);
}

// ---------------------------------------------------------------------------
// Fused fp32->bf16 convert for all 4 inputs (one launch).
// ---------------------------------------------------------------------------
__global__ __launch_bounds__(256) void cvt_all_kernel(
    const float* __restrict__ inputs, const float* __restrict__ queries,
    const float* __restrict__ w_in, const float* __restrict__ w_out,
    u16* __restrict__ ib, u16* __restrict__ qb,
    u16* __restrict__ wib, u16* __restrict__ wob)
{
    int blk = blockIdx.x;
    const float* s; u16* d; int base;
    if (blk < 8192)        { s = inputs;  d = ib;  base = blk; }
    else if (blk < 12288)  { s = queries; d = qb;  base = blk - 8192; }
    else if (blk < 15360)  { s = w_in;    d = wib; base = blk - 12288; }
    else                   { s = w_out;   d = wob; base = blk - 15360; }
    int i = base * 256 + threadIdx.x;
    float4 v = ((const float4*)s)[i];
    ushort4 o;
    o.x = f2bf(v.x); o.y = f2bf(v.y); o.z = f2bf(v.z); o.w = f2bf(v.w);
    ((ushort4*)d)[i] = o;
}

// ---------------------------------------------------------------------------
// Fused Q/K/V projection GEMM. 128x128 tile, BK=32, 256 threads (4 waves).
// by in [0,64): KV — A=inputs_b [8192,1024], W=w_in rows [1024,3072), N=2048.
//   cols <1024 -> Kb row-major bf16; cols >=1024 -> VTf in sigma'-permuted
//   frag order: VTf[g32][h][d][slot], slot = quad*8 + j where the token at
//   slot is g32*32 + (j<4 ? 4*quad+j : 16 + 4*quad + (j-4)).
// by in [64,96): Q (bx<8 only) — A=queries_b [4096,1024], W=w_in rows
//   [0,1024), out Qb row-major bf16.
// ---------------------------------------------------------------------------
__global__ __launch_bounds__(256) void proj_gemm_kernel(
    const u16* __restrict__ inputs_b, const u16* __restrict__ queries_b,
    const u16* __restrict__ w_in_b, const float* __restrict__ b_in,
    u16* __restrict__ Kb, u16* __restrict__ Qb, u16* __restrict__ VTf)
{
    __shared__ u16 As[128 * 32];
    __shared__ u16 Ws[128 * 32];

    const int bx = blockIdx.x;
    const int by = blockIdx.y;
    const bool isQ = (by >= 64);
    if (isQ && bx >= 8) return;

    const u16* A = isQ ? queries_b : inputs_b;
    const u16* W = w_in_b + (isQ ? 0 : (size_t)E_DIM * E_DIM);
    const float* bias = b_in + (isQ ? 0 : E_DIM);
    const int m_blk = (isQ ? by - 64 : by) * 128;
    const int n_blk = bx * 128;
    const int K = E_DIM;

    const int tid = threadIdx.x;
    const int l = tid & 63;
    const int w = tid >> 6;
    const int m0 = (w & 1) * 64;
    const int n0 = (w >> 1) * 64;
    const int quad = l >> 4;
    const int c = l & 15;

    f32x4 acc[4][4];
    #pragma unroll
    for (int i = 0; i < 4; ++i)
        #pragma unroll
        for (int j = 0; j < 4; ++j)
            acc[i][j] = (f32x4){0.f, 0.f, 0.f, 0.f};

    const int srow = l >> 2;
    const int skoff = (l & 3) * 8;
    const u16* Ag1 = A + (size_t)(m_blk + w * 16 + srow) * K + skoff;
    const u16* Ag2 = A + (size_t)(m_blk + (w + 4) * 16 + srow) * K + skoff;
    const u16* Wg1 = W + (size_t)(n_blk + w * 16 + srow) * K + skoff;
    const u16* Wg2 = W + (size_t)(n_blk + (w + 4) * 16 + srow) * K + skoff;

    for (int k0 = 0; k0 < K; k0 += 32) {
        __syncthreads();
        async16(Ag1 + k0, As + (size_t)w * 512);
        async16(Ag2 + k0, As + (size_t)(w + 4) * 512);
        async16(Wg1 + k0, Ws + (size_t)w * 512);
        async16(Wg2 + k0, Ws + (size_t)(w + 4) * 512);
        __syncthreads();

        bf16x8 af[4], wf[4];
        #pragma unroll
        for (int t = 0; t < 4; ++t) {
            af[t] = *(const bf16x8*)&As[(m0 + t * 16 + c) * 32 + quad * 8];
            wf[t] = *(const bf16x8*)&Ws[(n0 + t * 16 + c) * 32 + quad * 8];
        }
        #pragma unroll
        for (int i = 0; i < 4; ++i)
            #pragma unroll
            for (int j = 0; j < 4; ++j)
                acc[i][j] = __builtin_amdgcn_mfma_f32_16x16x32_bf16(
                    af[i], wf[j], acc[i][j], 0, 0, 0);
    }

    #pragma unroll
    for (int jj = 0; jj < 4; ++jj) {
        int col = n_blk + n0 + jj * 16 + c;
        float bv = bias[col];
        if (isQ) {
            #pragma unroll
            for (int i = 0; i < 4; ++i) {
                int row = m_blk + m0 + i * 16 + quad * 4;
                #pragma unroll
                for (int r = 0; r < 4; ++r)
                    Qb[(size_t)(row + r) * E_DIM + col] = f2bf(acc[i][jj][r] + bv);
            }
        } else if (col < 1024) {
            #pragma unroll
            for (int i = 0; i < 4; ++i) {
                int row = m_blk + m0 + i * 16 + quad * 4;
                #pragma unroll
                for (int r = 0; r < 4; ++r)
                    Kb[(size_t)(row + r) * E_DIM + col] = f2bf(acc[i][jj][r] + bv);
            }
        } else {
            int vcol = col - 1024;
            int h = vcol >> 6, d = vcol & 63;
            #pragma unroll
            for (int i = 0; i < 4; ++i) {
                int tok_base = m_blk + m0 + i * 16;        // multiple of 16
                int g32 = tok_base >> 5;
                int jo = (tok_base & 16) >> 2;             // 0 or 4
                ushort4 pk;
                pk.x = f2bf(acc[i][jj][0] + bv);
                pk.y = f2bf(acc[i][jj][1] + bv);
                pk.z = f2bf(acc[i][jj][2] + bv);
                pk.w = f2bf(acc[i][jj][3] + bv);
                *(ushort4*)(VTf + ((size_t)(g32 * NH + h) * 64 + d) * 32
                            + quad * 8 + jo) = pk;
            }
        }
    }
}

// ---------------------------------------------------------------------------
// Attention, S^T formulation, verified 16x16x32_bf16 only. No LDS/barriers.
// grid (LQ/64, NH, BSEG), 256 threads = 4 waves; wave handles 16 q rows.
// S^T = mfma(Kfrag, Qfrag): C row=kv(quad*4+r), col=q(lane&15). PV uses the
// kv-permutation sigma'(8q+j) = (j<4 ? 4q+j : 16+4q+j-4): A-frag is the
// lane's own p registers {tile0[0..3], tile1[0..3]}; V stored in VTf in the
// same sigma' order -> plain 16B coalesced B-frag loads.
// ---------------------------------------------------------------------------
__global__ __launch_bounds__(256) void attn_kernel(
    const u16* __restrict__ Qb, const u16* __restrict__ Kb,
    const u16* __restrict__ VTf, u16* __restrict__ Ob)
{
    const int tid = threadIdx.x;
    const int l = tid & 63;
    const int w = tid >> 6;
    const int quad = l >> 4;
    const int c = l & 15;
    const int h = blockIdx.y;
    const int b = blockIdx.z;
    const int q0 = b * LQ + blockIdx.x * 64 + w * 16;
    const int kcol = h * 64;
    const float C1 = 0.18033688011112042f;   // (1/8)*log2(e)

    // Q B-frags: lane holds Q[q0 + (l&15)][kcol + hk*32 + quad*8 ..]
    bf16x8 qf[2];
    #pragma unroll
    for (int hk = 0; hk < 2; ++hk)
        qf[hk] = *(const bf16x8*)(Qb + (size_t)(q0 + c) * E_DIM + kcol + hk * 32 + quad * 8);

    f32x4 o[4];
    #pragma unroll
    for (int td = 0; td < 4; ++td) o[td] = (f32x4){0.f, 0.f, 0.f, 0.f};
    float m_i = -1e30f, l_i = 0.f;

    for (int kv0 = 0; kv0 < LKV; kv0 += 64) {
        const int kvg = b * LKV + kv0;

        // S^T = K · Q^T (4 kv-tiles of 16)
        f32x4 s[4];
        #pragma unroll
        for (int nt = 0; nt < 4; ++nt) s[nt] = (f32x4){0.f, 0.f, 0.f, 0.f};
        #pragma unroll
        for (int nt = 0; nt < 4; ++nt) {
            #pragma unroll
            for (int hk = 0; hk < 2; ++hk) {
                bf16x8 kf = *(const bf16x8*)(Kb + (size_t)(kvg + nt * 16 + c) * E_DIM
                                             + kcol + hk * 32 + quad * 8);
                s[nt] = __builtin_amdgcn_mfma_f32_16x16x32_bf16(kf, qf[hk], s[nt], 0, 0, 0);
            }
        }

        // online softmax; lane state belongs to q = q0 + c (replicated / quads)
        float vm = -1e30f;
        #pragma unroll
        for (int nt = 0; nt < 4; ++nt)
            #pragma unroll
            for (int r = 0; r < 4; ++r) vm = fmaxf(vm, s[nt][r]);
        vm = fmaxf(vm, __shfl_xor(vm, 16, 64));
        vm = fmaxf(vm, __shfl_xor(vm, 32, 64));
        float mnew = fmaxf(m_i, vm);
        float alpha = __builtin_amdgcn_exp2f((m_i - mnew) * C1);
        m_i = mnew;

        float p[4][4];
        float rs = 0.f;
        #pragma unroll
        for (int nt = 0; nt < 4; ++nt)
            #pragma unroll
            for (int r = 0; r < 4; ++r) {
                p[nt][r] = __builtin_amdgcn_exp2f((s[nt][r] - mnew) * C1);
                rs += p[nt][r];
            }
        rs += __shfl_xor(rs, 16, 64);
        rs += __shfl_xor(rs, 32, 64);
        l_i = l_i * alpha + rs;

        // rescale O (O rows are q = quad*4+r; alpha lives at lane q = c)
        float ar[4];
        #pragma unroll
        for (int r = 0; r < 4; ++r) ar[r] = __shfl(alpha, quad * 4 + r, 16);
        #pragma unroll
        for (int td = 0; td < 4; ++td)
            #pragma unroll
            for (int r = 0; r < 4; ++r) o[td][r] *= ar[r];

        // A-frags for PV: sigma' puts the lane's own p regs in place
        bf16x8 af[2];
        #pragma unroll
        for (int g = 0; g < 2; ++g)
            #pragma unroll
            for (int r = 0; r < 4; ++r) {
                af[g][r]     = (short)f2bf(p[2 * g][r]);
                af[g][4 + r] = (short)f2bf(p[2 * g + 1][r]);
            }

        // O += P·V ; V B-frags from sigma'-ordered VTf (16B coalesced)
        #pragma unroll
        for (int g = 0; g < 2; ++g) {
            size_t vbase = (size_t)(((kvg >> 5) + g) * NH + h) * 2048;
            #pragma unroll
            for (int td = 0; td < 4; ++td) {
                bf16x8 vf = *(const bf16x8*)(VTf + vbase + (size_t)(td * 16 + c) * 32 + quad * 8);
                o[td] = __builtin_amdgcn_mfma_f32_16x16x32_bf16(af[g], vf, o[td], 0, 0, 0);
            }
        }
    }

    // epilogue: normalize (l_i lives at lane q=c; O rows are q=quad*4+r)
    float invl = 1.f / l_i;
    float ir[4];
    #pragma unroll
    for (int r = 0; r < 4; ++r) ir[r] = __shfl(invl, quad * 4 + r, 16);
    #pragma unroll
    for (int td = 0; td < 4; ++td)
        #pragma unroll
        for (int r = 0; r < 4; ++r)
            Ob[(size_t)(q0 + quad * 4 + r) * E_DIM + kcol + td * 16 + c] =
                f2bf(o[td][r] * ir[r]);
}

// ---------------------------------------------------------------------------
// Output projection: out[4096,1024] = Ob @ w_out^T + b_out (fp32 out).
// ---------------------------------------------------------------------------
__global__ __launch_bounds__(256) void out_gemm_kernel(
    const u16* __restrict__ A, const u16* __restrict__ W,
    const float* __restrict__ bias, float* __restrict__ Cf)
{
    __shared__ u16 As[128 * 32];
    __shared__ u16 Ws[128 * 32];

    const int K = E_DIM, N = E_DIM;
    const int tid = threadIdx.x;
    const int l = tid & 63;
    const int w = tid >> 6;
    const int m_blk = blockIdx.y * 128;
    const int n_blk = blockIdx.x * 128;
    const int m0 = (w & 1) * 64;
    const int n0 = (w >> 1) * 64;
    const int quad = l >> 4;
    const int c = l & 15;

    f32x4 acc[4][4];
    #pragma unroll
    for (int i = 0; i < 4; ++i)
        #pragma unroll
        for (int j = 0; j < 4; ++j)
            acc[i][j] = (f32x4){0.f, 0.f, 0.f, 0.f};

    const int srow = l >> 2;
    const int skoff = (l & 3) * 8;
    const u16* Ag1 = A + (size_t)(m_blk + w * 16 + srow) * K + skoff;
    const u16* Ag2 = A + (size_t)(m_blk + (w + 4) * 16 + srow) * K + skoff;
    const u16* Wg1 = W + (size_t)(n_blk + w * 16 + srow) * K + skoff;
    const u16* Wg2 = W + (size_t)(n_blk + (w + 4) * 16 + srow) * K + skoff;

    for (int k0 = 0; k0 < K; k0 += 32) {
        __syncthreads();
        async16(Ag1 + k0, As + (size_t)w * 512);
        async16(Ag2 + k0, As + (size_t)(w + 4) * 512);
        async16(Wg1 + k0, Ws + (size_t)w * 512);
        async16(Wg2 + k0, Ws + (size_t)(w + 4) * 512);
        __syncthreads();

        bf16x8 af[4], wf[4];
        #pragma unroll
        for (int t = 0; t < 4; ++t) {
            af[t] = *(const bf16x8*)&As[(m0 + t * 16 + c) * 32 + quad * 8];
            wf[t] = *(const bf16x8*)&Ws[(n0 + t * 16 + c) * 32 + quad * 8];
        }
        #pragma unroll
        for (int i = 0; i < 4; ++i)
            #pragma unroll
            for (int j = 0; j < 4; ++j)
                acc[i][j] = __builtin_amdgcn_mfma_f32_16x16x32_bf16(
                    af[i], wf[j], acc[i][j], 0, 0, 0);
    }

    #pragma unroll
    for (int j = 0; j < 4; ++j) {
        int col = n_blk + n0 + j * 16 + c;
        float bv = bias[col];
        #pragma unroll
        for (int i = 0; i < 4; ++i) {
            int row = m_blk + m0 + i * 16 + quad * 4;
            #pragma unroll
            for (int r = 0; r < 4; ++r)
                Cf[(size_t)(row + r) * N + col] = acc[i][j][r] + bv;
        }
    }
}

// ---------------------------------------------------------------------------
extern "C" void kernel_launch(void* const* d_in, const int* in_sizes, int n_in,
                              void* d_out, int out_size, void* d_ws, size_t ws_size,
                              hipStream_t stream) {
    const float* inputs  = (const float*)d_in[0];   // [8192,1024]
    const float* queries = (const float*)d_in[1];   // [4096,1024]
    const float* w_in    = (const float*)d_in[2];   // [3072,1024]
    const float* b_in    = (const float*)d_in[3];   // [3072]
    const float* w_out   = (const float*)d_in[4];   // [1024,1024]
    const float* b_out   = (const float*)d_in[5];   // [1024]
    float* out = (float*)d_out;                     // [4096,1024] fp32

    const int NQ = BSEG * LQ;    // 4096
    const int NKV = BSEG * LKV;  // 8192

    // workspace: 80 MB
    u16* inputs_b  = (u16*)d_ws;                                   // 16 MB
    u16* queries_b = inputs_b  + (size_t)NKV * E_DIM;              //  8 MB
    u16* w_in_b    = queries_b + (size_t)NQ * E_DIM;               //  6 MB
    u16* w_out_b   = w_in_b    + (size_t)3 * E_DIM * E_DIM;        //  2 MB
    u16* Qb        = w_out_b   + (size_t)E_DIM * E_DIM;            //  8 MB
    u16* Kb        = Qb        + (size_t)NQ * E_DIM;               // 16 MB
    u16* VTf       = Kb        + (size_t)NKV * E_DIM;              // 16 MB
    u16* Ob        = VTf       + (size_t)NKV * E_DIM;              //  8 MB

    dim3 blk(256);

    cvt_all_kernel<<<16384, blk, 0, stream>>>(
        inputs, queries, w_in, w_out, inputs_b, queries_b, w_in_b, w_out_b);

    proj_gemm_kernel<<<dim3(16, 96), blk, 0, stream>>>(
        inputs_b, queries_b, w_in_b, b_in, Kb, Qb, VTf);

    attn_kernel<<<dim3(LQ / 64, NH, BSEG), blk, 0, stream>>>(Qb, Kb, VTf, Ob);

    out_gemm_kernel<<<dim3(E_DIM / 128, NQ / 128), blk, 0, stream>>>(
        Ob, w_out_b, b_out, out);
}

// Round 5
// 249.110 us; speedup vs baseline: 4.4623x; 1.1926x over previous
//
#include <hip/hip_runtime.h>

#define E_DIM 1024
#define NH 16
#define DH 64
#define BSEG 8
#define LQ 512
#define LKV 1024

typedef short bf16x8 __attribute__((ext_vector_type(8)));
typedef float f32x4 __attribute__((ext_vector_type(4)));
typedef unsigned short u16;

// round-to-nearest-even fp32 -> bf16 bits
__device__ __forceinline__ u16 f2bf(float x) {
    unsigned u = __float_as_uint(x);
    u += 0x7FFF + ((u >> 16) & 1);
    return (u16)(u >> 16);
}

// async global->LDS, 16B per lane; lds dest wave-uniform base + lane*16
__device__ __forceinline__ void async16(const void* g, const void* l) {
    __builtin_amdgcn_global_load_lds(
        (const __attribute__((address_space(1))) unsigned int*)g,
        (__attribute__((address_space(3))) unsigned int*)l, 16, 0, 0);
}

// ---------------------------------------------------------------------------
// Fused fp32->bf16 convert for all 4 inputs (one launch).
// ---------------------------------------------------------------------------
__global__ __launch_bounds__(256) void cvt_all_kernel(
    const float* __restrict__ inputs, const float* __restrict__ queries,
    const float* __restrict__ w_in, const float* __restrict__ w_out,
    u16* __restrict__ ib, u16* __restrict__ qb,
    u16* __restrict__ wib, u16* __restrict__ wob)
{
    int blk = blockIdx.x;
    const float* s; u16* d; int base;
    if (blk < 8192)        { s = inputs;  d = ib;  base = blk; }
    else if (blk < 12288)  { s = queries; d = qb;  base = blk - 8192; }
    else if (blk < 15360)  { s = w_in;    d = wib; base = blk - 12288; }
    else                   { s = w_out;   d = wob; base = blk - 15360; }
    int i = base * 256 + threadIdx.x;
    float4 v = ((const float4*)s)[i];
    ushort4 o;
    o.x = f2bf(v.x); o.y = f2bf(v.y); o.z = f2bf(v.z); o.w = f2bf(v.w);
    ((ushort4*)d)[i] = o;
}

// ---------------------------------------------------------------------------
// Fused Q/K/V projection GEMM. 128x128 tile, BK=32, 256 threads (4 waves).
// Epilogues write attention-native layouts:
//   Qf/Kf "frag16": chunk per (token-tile t = tok>>4, head h), 1024 shorts;
//     element (token=16t+tc, d) at (d>>3)*128 + tc*8 + (d&7)  -> attention
//     A/B frag load = chunk + hk*512 + lane*8 (fully coalesced 16B/lane).
//   Vf "sigma'-frag": chunk per (g32 = tok>>5, h), 2048 shorts; element
//     (token = 32*g32 + sigma'(8q+j), d) at ((td*4+q)*16 + (d&15))*8 + j,
//     td = (d&63)>>4; sigma'(8q+j) = j<4 ? 4q+j : 16+4q+(j-4).
// by in [0,64): KV — A=inputs_b, W=w_in rows [1024,3072), N=2048.
// by in [64,96): Q (bx<8) — A=queries_b, W=w_in rows [0,1024).
// ---------------------------------------------------------------------------
__global__ __launch_bounds__(256) void proj_gemm_kernel(
    const u16* __restrict__ inputs_b, const u16* __restrict__ queries_b,
    const u16* __restrict__ w_in_b, const float* __restrict__ b_in,
    u16* __restrict__ Kf, u16* __restrict__ Qf, u16* __restrict__ Vf)
{
    __shared__ u16 As[128 * 32];
    __shared__ u16 Ws[128 * 32];

    const int bx = blockIdx.x;
    const int by = blockIdx.y;
    const bool isQ = (by >= 64);
    if (isQ && bx >= 8) return;

    const u16* A = isQ ? queries_b : inputs_b;
    const u16* W = w_in_b + (isQ ? 0 : (size_t)E_DIM * E_DIM);
    const float* bias = b_in + (isQ ? 0 : E_DIM);
    const int m_blk = (isQ ? by - 64 : by) * 128;
    const int n_blk = bx * 128;
    const int K = E_DIM;

    const int tid = threadIdx.x;
    const int l = tid & 63;
    const int w = tid >> 6;
    const int m0 = (w & 1) * 64;
    const int n0 = (w >> 1) * 64;
    const int quad = l >> 4;
    const int c = l & 15;

    f32x4 acc[4][4];
    #pragma unroll
    for (int i = 0; i < 4; ++i)
        #pragma unroll
        for (int j = 0; j < 4; ++j)
            acc[i][j] = (f32x4){0.f, 0.f, 0.f, 0.f};

    const int srow = l >> 2;
    const int skoff = (l & 3) * 8;
    const u16* Ag1 = A + (size_t)(m_blk + w * 16 + srow) * K + skoff;
    const u16* Ag2 = A + (size_t)(m_blk + (w + 4) * 16 + srow) * K + skoff;
    const u16* Wg1 = W + (size_t)(n_blk + w * 16 + srow) * K + skoff;
    const u16* Wg2 = W + (size_t)(n_blk + (w + 4) * 16 + srow) * K + skoff;

    for (int k0 = 0; k0 < K; k0 += 32) {
        __syncthreads();
        async16(Ag1 + k0, As + (size_t)w * 512);
        async16(Ag2 + k0, As + (size_t)(w + 4) * 512);
        async16(Wg1 + k0, Ws + (size_t)w * 512);
        async16(Wg2 + k0, Ws + (size_t)(w + 4) * 512);
        __syncthreads();

        bf16x8 af[4], wf[4];
        #pragma unroll
        for (int t = 0; t < 4; ++t) {
            af[t] = *(const bf16x8*)&As[(m0 + t * 16 + c) * 32 + quad * 8];
            wf[t] = *(const bf16x8*)&Ws[(n0 + t * 16 + c) * 32 + quad * 8];
        }
        #pragma unroll
        for (int i = 0; i < 4; ++i)
            #pragma unroll
            for (int j = 0; j < 4; ++j)
                acc[i][j] = __builtin_amdgcn_mfma_f32_16x16x32_bf16(
                    af[i], wf[j], acc[i][j], 0, 0, 0);
    }

    #pragma unroll
    for (int jj = 0; jj < 4; ++jj) {
        int col = n_blk + n0 + jj * 16 + c;
        float bv = bias[col];
        if (isQ || col < 1024) {
            u16* dst = isQ ? Qf : Kf;
            int hh = col >> 6, d = col & 63;
            int dq = d >> 3, dj = d & 7;
            #pragma unroll
            for (int i = 0; i < 4; ++i) {
                int t = (m_blk + m0 + i * 16) >> 4;
                size_t base = ((size_t)(t * NH + hh)) * 1024
                            + (size_t)(dq * 16 + quad * 4) * 8 + dj;
                #pragma unroll
                for (int r = 0; r < 4; ++r)
                    dst[base + (size_t)r * 8] = f2bf(acc[i][jj][r] + bv);
            }
        } else {
            int vcol = col - 1024;
            int hv = vcol >> 6, d = vcol & 63;
            int td = d >> 4, ct = d & 15;
            #pragma unroll
            for (int i = 0; i < 4; ++i) {
                int tok = m_blk + m0 + i * 16;
                int g32 = tok >> 5;
                int jo = (tok & 16) >> 2;          // 0 or 4
                ushort4 pk;
                pk.x = f2bf(acc[i][jj][0] + bv);
                pk.y = f2bf(acc[i][jj][1] + bv);
                pk.z = f2bf(acc[i][jj][2] + bv);
                pk.w = f2bf(acc[i][jj][3] + bv);
                *(ushort4*)(Vf + ((size_t)(g32 * NH + hv)) * 2048
                            + (size_t)((td * 4 + quad) * 16 + ct) * 8 + jo) = pk;
            }
        }
    }
}

// ---------------------------------------------------------------------------
// Attention, S^T formulation; frag-ordered operands; no LDS/barriers.
// 1D grid 1024: bid = qt*128 + b*16 + h  -> bid%8 = h%8: all 8 q-tiles of a
// given (b,h) share one XCD (L2 reuse of K/V). 256 thr = 4 waves x 16 q rows.
// K/V frags register-double-buffered to hide global latency behind softmax.
// ---------------------------------------------------------------------------
struct KVfrags { bf16x8 kf[4][2]; bf16x8 vf[2][4]; };

__global__ __launch_bounds__(256) void attn_kernel(
    const u16* __restrict__ Qf, const u16* __restrict__ Kf,
    const u16* __restrict__ Vf, u16* __restrict__ Ob)
{
    const int tid = threadIdx.x;
    const int l = tid & 63;
    const int w = tid >> 6;
    const int quad = l >> 4;
    const int c = l & 15;
    const int bid = blockIdx.x;
    const int h = bid & 15;
    const int b = (bid >> 4) & 7;
    const int qt = bid >> 7;
    const int q0 = b * LQ + qt * 64 + w * 16;
    const float C1 = 0.18033688011112042f;   // (1/8)*log2(e)

    // Q B-frags (frag16 layout: fully coalesced)
    bf16x8 qf[2];
    {
        size_t qb = ((size_t)((q0 >> 4) * NH + h)) * 1024 + (size_t)l * 8;
        qf[0] = *(const bf16x8*)(Qf + qb);
        qf[1] = *(const bf16x8*)(Qf + qb + 512);
    }

    f32x4 o[4];
    #pragma unroll
    for (int td = 0; td < 4; ++td) o[td] = (f32x4){0.f, 0.f, 0.f, 0.f};
    float m_i = -1e30f, l_i = 0.f;

    auto load_kv = [&](int kv0, KVfrags& dst) {
        const int kvg = b * LKV + kv0;
        #pragma unroll
        for (int nt = 0; nt < 4; ++nt) {
            size_t kb = ((size_t)((((kvg >> 4) + nt) * NH) + h)) * 1024 + (size_t)l * 8;
            dst.kf[nt][0] = *(const bf16x8*)(Kf + kb);
            dst.kf[nt][1] = *(const bf16x8*)(Kf + kb + 512);
        }
        #pragma unroll
        for (int g = 0; g < 2; ++g) {
            size_t vb = ((size_t)((((kvg >> 5) + g) * NH) + h)) * 2048 + (size_t)l * 8;
            #pragma unroll
            for (int td = 0; td < 4; ++td)
                dst.vf[g][td] = *(const bf16x8*)(Vf + vb + td * 512);
        }
    };

    auto step = [&](KVfrags& cv) {
        // S^T = K · Q^T (4 kv-tiles of 16)
        f32x4 s[4];
        #pragma unroll
        for (int nt = 0; nt < 4; ++nt) s[nt] = (f32x4){0.f, 0.f, 0.f, 0.f};
        #pragma unroll
        for (int nt = 0; nt < 4; ++nt)
            #pragma unroll
            for (int hk = 0; hk < 2; ++hk)
                s[nt] = __builtin_amdgcn_mfma_f32_16x16x32_bf16(
                    cv.kf[nt][hk], qf[hk], s[nt], 0, 0, 0);

        // online softmax; lane state belongs to q = q0 + c (replicated / quads)
        float vm = -1e30f;
        #pragma unroll
        for (int nt = 0; nt < 4; ++nt)
            #pragma unroll
            for (int r = 0; r < 4; ++r) vm = fmaxf(vm, s[nt][r]);
        vm = fmaxf(vm, __shfl_xor(vm, 16, 64));
        vm = fmaxf(vm, __shfl_xor(vm, 32, 64));
        float mnew = fmaxf(m_i, vm);
        float alpha = __builtin_amdgcn_exp2f((m_i - mnew) * C1);
        m_i = mnew;

        float p[4][4];
        float rs = 0.f;
        #pragma unroll
        for (int nt = 0; nt < 4; ++nt)
            #pragma unroll
            for (int r = 0; r < 4; ++r) {
                p[nt][r] = __builtin_amdgcn_exp2f((s[nt][r] - mnew) * C1);
                rs += p[nt][r];
            }
        rs += __shfl_xor(rs, 16, 64);
        rs += __shfl_xor(rs, 32, 64);
        l_i = l_i * alpha + rs;

        // rescale O (O rows are q = quad*4+r; alpha lives at lane q = c)
        float ar[4];
        #pragma unroll
        for (int r = 0; r < 4; ++r) ar[r] = __shfl(alpha, quad * 4 + r, 16);
        #pragma unroll
        for (int td = 0; td < 4; ++td)
            #pragma unroll
            for (int r = 0; r < 4; ++r) o[td][r] *= ar[r];

        // A-frags for PV: sigma' puts the lane's own p regs in place
        bf16x8 af[2];
        #pragma unroll
        for (int g = 0; g < 2; ++g)
            #pragma unroll
            for (int r = 0; r < 4; ++r) {
                af[g][r]     = (short)f2bf(p[2 * g][r]);
                af[g][4 + r] = (short)f2bf(p[2 * g + 1][r]);
            }

        #pragma unroll
        for (int g = 0; g < 2; ++g)
            #pragma unroll
            for (int td = 0; td < 4; ++td)
                o[td] = __builtin_amdgcn_mfma_f32_16x16x32_bf16(
                    af[g], cv.vf[g][td], o[td], 0, 0, 0);
    };

    // software-pipelined: prefetch next 64-kv chunk while computing current
    KVfrags bufA, bufB;
    load_kv(0, bufA);
    #pragma unroll
    for (int it = 0; it < 16; it += 2) {
        if (it + 1 < 16) load_kv((it + 1) * 64, bufB);
        step(bufA);
        if (it + 2 < 16) load_kv((it + 2) * 64, bufA);
        if (it + 1 < 16) step(bufB);
    }

    // epilogue: normalize (l_i lives at lane q=c; O rows are q=quad*4+r)
    float invl = 1.f / l_i;
    float ir[4];
    #pragma unroll
    for (int r = 0; r < 4; ++r) ir[r] = __shfl(invl, quad * 4 + r, 16);
    #pragma unroll
    for (int td = 0; td < 4; ++td)
        #pragma unroll
        for (int r = 0; r < 4; ++r)
            Ob[(size_t)(q0 + quad * 4 + r) * E_DIM + h * 64 + td * 16 + c] =
                f2bf(o[td][r] * ir[r]);
}

// ---------------------------------------------------------------------------
// Output projection: out[4096,1024] = Ob @ w_out^T + b_out (fp32 out).
// ---------------------------------------------------------------------------
__global__ __launch_bounds__(256) void out_gemm_kernel(
    const u16* __restrict__ A, const u16* __restrict__ W,
    const float* __restrict__ bias, float* __restrict__ Cf)
{
    __shared__ u16 As[128 * 32];
    __shared__ u16 Ws[128 * 32];

    const int K = E_DIM, N = E_DIM;
    const int tid = threadIdx.x;
    const int l = tid & 63;
    const int w = tid >> 6;
    const int m_blk = blockIdx.y * 128;
    const int n_blk = blockIdx.x * 128;
    const int m0 = (w & 1) * 64;
    const int n0 = (w >> 1) * 64;
    const int quad = l >> 4;
    const int c = l & 15;

    f32x4 acc[4][4];
    #pragma unroll
    for (int i = 0; i < 4; ++i)
        #pragma unroll
        for (int j = 0; j < 4; ++j)
            acc[i][j] = (f32x4){0.f, 0.f, 0.f, 0.f};

    const int srow = l >> 2;
    const int skoff = (l & 3) * 8;
    const u16* Ag1 = A + (size_t)(m_blk + w * 16 + srow) * K + skoff;
    const u16* Ag2 = A + (size_t)(m_blk + (w + 4) * 16 + srow) * K + skoff;
    const u16* Wg1 = W + (size_t)(n_blk + w * 16 + srow) * K + skoff;
    const u16* Wg2 = W + (size_t)(n_blk + (w + 4) * 16 + srow) * K + skoff;

    for (int k0 = 0; k0 < K; k0 += 32) {
        __syncthreads();
        async16(Ag1 + k0, As + (size_t)w * 512);
        async16(Ag2 + k0, As + (size_t)(w + 4) * 512);
        async16(Wg1 + k0, Ws + (size_t)w * 512);
        async16(Wg2 + k0, Ws + (size_t)(w + 4) * 512);
        __syncthreads();

        bf16x8 af[4], wf[4];
        #pragma unroll
        for (int t = 0; t < 4; ++t) {
            af[t] = *(const bf16x8*)&As[(m0 + t * 16 + c) * 32 + quad * 8];
            wf[t] = *(const bf16x8*)&Ws[(n0 + t * 16 + c) * 32 + quad * 8];
        }
        #pragma unroll
        for (int i = 0; i < 4; ++i)
            #pragma unroll
            for (int j = 0; j < 4; ++j)
                acc[i][j] = __builtin_amdgcn_mfma_f32_16x16x32_bf16(
                    af[i], wf[j], acc[i][j], 0, 0, 0);
    }

    #pragma unroll
    for (int j = 0; j < 4; ++j) {
        int col = n_blk + n0 + j * 16 + c;
        float bv = bias[col];
        #pragma unroll
        for (int i = 0; i < 4; ++i) {
            int row = m_blk + m0 + i * 16 + quad * 4;
            #pragma unroll
            for (int r = 0; r < 4; ++r)
                Cf[(size_t)(row + r) * N + col] = acc[i][j][r] + bv;
        }
    }
}

// ---------------------------------------------------------------------------
extern "C" void kernel_launch(void* const* d_in, const int* in_sizes, int n_in,
                              void* d_out, int out_size, void* d_ws, size_t ws_size,
                              hipStream_t stream) {
    const float* inputs  = (const float*)d_in[0];   // [8192,1024]
    const float* queries = (const float*)d_in[1];   // [4096,1024]
    const float* w_in    = (const float*)d_in[2];   // [3072,1024]
    const float* b_in    = (const float*)d_in[3];   // [3072]
    const float* w_out   = (const float*)d_in[4];   // [1024,1024]
    const float* b_out   = (const float*)d_in[5];   // [1024]
    float* out = (float*)d_out;                     // [4096,1024] fp32

    const int NQ = BSEG * LQ;    // 4096
    const int NKV = BSEG * LKV;  // 8192

    // workspace: 80 MB
    u16* inputs_b  = (u16*)d_ws;                                   // 16 MB
    u16* queries_b = inputs_b  + (size_t)NKV * E_DIM;              //  8 MB
    u16* w_in_b    = queries_b + (size_t)NQ * E_DIM;               //  6 MB
    u16* w_out_b   = w_in_b    + (size_t)3 * E_DIM * E_DIM;        //  2 MB
    u16* Qf        = w_out_b   + (size_t)E_DIM * E_DIM;            //  8 MB
    u16* Kf        = Qf        + (size_t)NQ * E_DIM;               // 16 MB
    u16* Vf        = Kf        + (size_t)NKV * E_DIM;              // 16 MB
    u16* Ob        = Vf        + (size_t)NKV * E_DIM;              //  8 MB

    dim3 blk(256);

    cvt_all_kernel<<<16384, blk, 0, stream>>>(
        inputs, queries, w_in, w_out, inputs_b, queries_b, w_in_b, w_out_b);

    proj_gemm_kernel<<<dim3(16, 96), blk, 0, stream>>>(
        inputs_b, queries_b, w_in_b, b_in, Kf, Qf, Vf);

    attn_kernel<<<1024, blk, 0, stream>>>(Qf, Kf, Vf, Ob);

    out_gemm_kernel<<<dim3(E_DIM / 128, NQ / 128), blk, 0, stream>>>(
        Ob, w_out_b, b_out, out);
}